// Round 1
// baseline (478.222 us; speedup 1.0000x reference)
//
#include <hip/hip_runtime.h>
#include <cfloat>

#define BLK 256
#define RED_BLOCKS 256

// ---------------- Kernel 1: per-block min/max partials ----------------
__global__ void k_minmax_partial(const float* __restrict__ x, int n4,
                                 float* __restrict__ partial) {
    const float4* __restrict__ x4 = (const float4*)x;
    float mn = FLT_MAX, mx = -FLT_MAX;
    for (int i = blockIdx.x * blockDim.x + threadIdx.x; i < n4;
         i += gridDim.x * blockDim.x) {
        float4 v = x4[i];
        mn = fminf(mn, fminf(fminf(v.x, v.y), fminf(v.z, v.w)));
        mx = fmaxf(mx, fmaxf(fmaxf(v.x, v.y), fmaxf(v.z, v.w)));
    }
    // wave-64 shuffle reduce
    for (int off = 32; off > 0; off >>= 1) {
        mn = fminf(mn, __shfl_down(mn, off, 64));
        mx = fmaxf(mx, __shfl_down(mx, off, 64));
    }
    __shared__ float smn[BLK / 64], smx[BLK / 64];
    int lane = threadIdx.x & 63;
    int w = threadIdx.x >> 6;
    if (lane == 0) { smn[w] = mn; smx[w] = mx; }
    __syncthreads();
    if (threadIdx.x == 0) {
        mn = smn[0]; mx = smx[0];
        for (int j = 1; j < BLK / 64; ++j) {
            mn = fminf(mn, smn[j]);
            mx = fmaxf(mx, smx[j]);
        }
        partial[2 * blockIdx.x]     = mn;
        partial[2 * blockIdx.x + 1] = mx;
    }
}

// ---------------- Kernel 2: final reduce -> params ----------------
__global__ void k_minmax_final(const float* __restrict__ partial, int nb,
                               float* __restrict__ params) {
    float mn = FLT_MAX, mx = -FLT_MAX;
    for (int i = threadIdx.x; i < nb; i += blockDim.x) {
        mn = fminf(mn, partial[2 * i]);
        mx = fmaxf(mx, partial[2 * i + 1]);
    }
    for (int off = 32; off > 0; off >>= 1) {
        mn = fminf(mn, __shfl_down(mn, off, 64));
        mx = fmaxf(mx, __shfl_down(mx, off, 64));
    }
    __shared__ float smn[BLK / 64], smx[BLK / 64];
    int lane = threadIdx.x & 63;
    int w = threadIdx.x >> 6;
    if (lane == 0) { smn[w] = mn; smx[w] = mx; }
    __syncthreads();
    if (threadIdx.x == 0) {
        mn = smn[0]; mx = smx[0];
        for (int j = 1; j < BLK / 64; ++j) {
            mn = fminf(mn, smn[j]);
            mx = fmaxf(mx, smx[j]);
        }
        params[0] = mn;
        params[1] = (mx - mn) + 1e-8f;  // exact fp32, same as ref
    }
}

// ---------------- Kernel 3: write one-hot spike planes ----------------
// One thread handles 4 consecutive spatial elements; loops over T planes.
__global__ void k_spikes(const float* __restrict__ x,
                         const float* __restrict__ params,
                         const int* __restrict__ Tptr,
                         float* __restrict__ out, int CHW, int n4) {
    int i = blockIdx.x * blockDim.x + threadIdx.x;  // float4 index
    if (i >= n4) return;
    const int T = Tptr[0];
    const float mn = params[0];
    const float d  = params[1];
    const float scaleT = (float)(T - 1);

    float4 v = ((const float4*)x)[i];

    // EXACT fp32 semantics of the reference: xn=(x-mn)/d; st=trunc((1-xn)*(T-1))
    float s0 = (1.0f - (v.x - mn) / d) * scaleT;
    float s1 = (1.0f - (v.y - mn) / d) * scaleT;
    float s2 = (1.0f - (v.z - mn) / d) * scaleT;
    float s3 = (1.0f - (v.w - mn) / d) * scaleT;
    int st0 = (int)s0; st0 = min(max(st0, 0), T - 1);
    int st1 = (int)s1; st1 = min(max(st1, 0), T - 1);
    int st2 = (int)s2; st2 = min(max(st2, 0), T - 1);
    int st3 = (int)s3; st3 = min(max(st3, 0), T - 1);

    int s4 = i * 4;                 // flat spatial index (b*CHW + r)
    int b  = s4 / CHW;
    int r  = s4 - b * CHW;
    float* obase = out + (size_t)b * (size_t)T * (size_t)CHW + (size_t)r;

    for (int t = 0; t < T; ++t) {
        float4 o;
        o.x = (t == st0) ? 1.0f : 0.0f;
        o.y = (t == st1) ? 1.0f : 0.0f;
        o.z = (t == st2) ? 1.0f : 0.0f;
        o.w = (t == st3) ? 1.0f : 0.0f;
        *(float4*)(obase + (size_t)t * (size_t)CHW) = o;
    }
}

extern "C" void kernel_launch(void* const* d_in, const int* in_sizes, int n_in,
                              void* d_out, int out_size, void* d_ws, size_t ws_size,
                              hipStream_t stream) {
    const float* x   = (const float*)d_in[0];
    const int* Tptr  = (const int*)d_in[1];
    float* out       = (float*)d_out;

    const int n  = in_sizes[0];   // 8*3*224*224 = 1,204,224
    const int n4 = n / 4;         // divisible (W=224)
    const int B  = 8;             // from reference setup
    const int CHW = n / B;        // 150,528

    float* partial = (float*)d_ws;           // 2*RED_BLOCKS floats
    float* params  = partial + 2 * RED_BLOCKS;

    k_minmax_partial<<<RED_BLOCKS, BLK, 0, stream>>>(x, n4, partial);
    k_minmax_final<<<1, BLK, 0, stream>>>(partial, RED_BLOCKS, params);

    int blocks = (n4 + BLK - 1) / BLK;       // 1176
    k_spikes<<<blocks, BLK, 0, stream>>>(x, params, Tptr, out, CHW, n4);
}